// Round 17
// baseline (546.178 us; speedup 1.0000x reference)
//
#include <hip/hip_runtime.h>
#include <math.h>

#define NN 50000
#define EE 800000
#define INC 128
#define HIDC 64
#define OUTC 64
#define LLAYERS 8
#define TOT (EE + NN)
#define NB 196            // col buckets of 256 cols (196*256 = 50176 >= NN)
#define ABLK 256          // phase-A blocks: 1/CU; runs ~17 entries (~68B, ~2 lines)
#define CHUNKA ((TOT + ABLK - 1) / ABLK)

// Wave-internal LDS fence (vecs[w]/xs[w] wave-private; no block barrier).
#define WAVE_LDS_FENCE() asm volatile("s_waitcnt lgkmcnt(0)" ::: "memory")

// bf16 <-> f32 (RTN-even pack; values are finite)
__device__ __forceinline__ float bf2f(unsigned short u) {
    return __uint_as_float(((unsigned int)u) << 16);
}
__device__ __forceinline__ unsigned short f2bf(float f) {
    unsigned int u = __float_as_uint(f);
    u += 0x7FFFu + ((u >> 16) & 1u);
    return (unsigned short)(u >> 16);
}
// Broadcast from a compile-time lane (valid: source lanes 0..15 hold aggv).
__device__ __forceinline__ float rl(float v, int srclane) {
    return __uint_as_float(__builtin_amdgcn_readlane(__float_as_uint(v), srclane));
}

// ---------------------------------------------------------------------------
// Stage 0: int64-vs-int32 detect, sampled (256 int64 views; misdetect needs
// 128 consecutive zero odd-words in int32 data: P ~ 0).
__global__ void detect_kernel(const long long* __restrict__ p, int* __restrict__ flag) {
    long long v = p[threadIdx.x];
    if (v < 0 || v >= NN) atomicOr(flag, 1);   // flag=1 -> int32 layout
}

__device__ __forceinline__ int load_row(const void* ei, int is64, int e) {
    return is64 ? (int)((const long long*)ei)[e] : ((const int*)ei)[e];
}
__device__ __forceinline__ int load_col(const void* ei, int is64, int e) {
    return is64 ? (int)((const long long*)ei)[EE + e] : ((const int*)ei)[EE + e];
}

// ---------------------------------------------------------------------------
// CSR build, phase A0: per-bucket edge counts.
__global__ __launch_bounds__(256) void histA(const void* __restrict__ ei,
                                             const int* __restrict__ flag,
                                             int* __restrict__ bcnt) {
    __shared__ int h[NB];
    int tid = threadIdx.x;
    for (int i = tid; i < NB; i += 256) h[i] = 0;
    __syncthreads();
    int is64 = (*flag == 0);
    int lo = blockIdx.x * CHUNKA, hi = lo + CHUNKA; if (hi > TOT) hi = TOT;
    for (int e = lo + tid; e < hi; e += 256) {
        int c = (e < EE) ? load_col(ei, is64, e) : (e - EE);
        atomicAdd(&h[c >> 8], 1);
    }
    __syncthreads();
    for (int i = tid; i < NB; i += 256) if (h[i]) atomicAdd(&bcnt[i], h[i]);
}

// phase A1: exclusive scan of bucket counts -> bstart[NB+1], bcur init.
__global__ __launch_bounds__(256) void scan_buckets(const int* __restrict__ bcnt,
                                                    int* __restrict__ bstart,
                                                    int* __restrict__ bcur) {
    __shared__ int s[256];
    int t = threadIdx.x;
    int v = (t < NB) ? bcnt[t] : 0;
    s[t] = v;
    __syncthreads();
    for (int off = 1; off < 256; off <<= 1) {
        int a = (t >= off) ? s[t - off] : 0;
        __syncthreads();
        s[t] += a;
        __syncthreads();
    }
    if (t < NB) { int st = s[t] - v; bstart[t] = st; bcur[t] = st; }
    if (t == NB - 1) bstart[NB] = s[t];
}

// phase A2: scatter PACKED (src<<8 | col&255) into bucket-major barr.
// 256 blocks x 196 buckets: runs ~17x4B, ~2 lines -> amp ~2x on 3.4MB.
__global__ __launch_bounds__(256) void bucket_scatter(const void* __restrict__ ei,
                                                      const int* __restrict__ flag,
                                                      int* __restrict__ bcur,
                                                      unsigned int* __restrict__ barr) {
    __shared__ int h[NB];
    __shared__ int base[NB];
    int tid = threadIdx.x;
    for (int i = tid; i < NB; i += 256) h[i] = 0;
    __syncthreads();
    int is64 = (*flag == 0);
    int lo = blockIdx.x * CHUNKA, hi = lo + CHUNKA; if (hi > TOT) hi = TOT;
    for (int e = lo + tid; e < hi; e += 256) {
        int c = (e < EE) ? load_col(ei, is64, e) : (e - EE);
        atomicAdd(&h[c >> 8], 1);
    }
    __syncthreads();
    for (int i = tid; i < NB; i += 256) {
        int cnt = h[i];
        base[i] = cnt ? atomicAdd(&bcur[i], cnt) : 0;
        h[i] = 0;                                   // reuse as local cursor
    }
    __syncthreads();
    for (int e = lo + tid; e < hi; e += 256) {
        int r, c;
        if (e < EE) { r = load_row(ei, is64, e); c = load_col(ei, is64, e); }
        else        { r = e - EE; c = r; }
        int b = c >> 8;
        int p = base[b] + atomicAdd(&h[b], 1);
        barr[p] = ((unsigned int)r << 8) | (unsigned int)(c & 255);
    }
}

// phase B0: per-bucket count + in-block scan -> GLOBAL CSR offsets + dinv.
// (Buckets partition cols in order, so bstart[b]+prefix IS the global offset.
// Replaces bucket_degcnt + dinv_kernel + scan_part/bsum/final.)
__global__ __launch_bounds__(256) void bucket_offsets(const unsigned int* __restrict__ barr,
                                                      const int* __restrict__ bstart,
                                                      int* __restrict__ offsets,
                                                      float* __restrict__ dinv) {
    __shared__ int cnt[256];
    __shared__ int pre[256];
    int b = blockIdx.x, t = threadIdx.x;
    cnt[t] = 0;
    __syncthreads();
    int lo = bstart[b], hi = bstart[b + 1];
    for (int i = lo + t; i < hi; i += 256) atomicAdd(&cnt[barr[i] & 255u], 1);
    __syncthreads();
    int v = cnt[t];
    pre[t] = v;
    __syncthreads();
    for (int off = 1; off < 256; off <<= 1) {
        int a = (t >= off) ? pre[t - off] : 0;
        __syncthreads();
        pre[t] += a;
        __syncthreads();
    }
    int c = (b << 8) + t;
    if (c <= NN) offsets[c] = bstart[b] + pre[t] - v;   // exclusive prefix
    if (c < NN)  dinv[c] = 1.0f / sqrtf((float)v);      // deg >= 1 (self-loop)
}

// phase B1: place into adj via LDS cursors (init from offsets); writes land in
// a contiguous ~35KB per-bucket window -> L2-dense.
__global__ __launch_bounds__(256) void bucket_place(const unsigned int* __restrict__ barr,
                                                    const int* __restrict__ bstart,
                                                    const int* __restrict__ offsets,
                                                    const float* __restrict__ dinv,
                                                    int2* __restrict__ adj) {
    __shared__ int cur[256];
    int b = blockIdx.x, t = threadIdx.x;
    int c0 = b << 8;
    int c = c0 + t;
    cur[t] = (c < NN) ? offsets[c] : 0;
    __syncthreads();
    int lo = bstart[b], hi = bstart[b + 1];
    for (int i = lo + t; i < hi; i += 256) {
        unsigned int v = barr[i];
        int r = (int)(v >> 8);
        int ci = (int)(v & 255u);
        int pos = atomicAdd(&cur[ci], 1);
        adj[pos] = make_int2(r, __float_as_int(dinv[r] * dinv[c0 + ci]));
    }
}

// ---------------------------------------------------------------------------
// Stage 4: h(bf16) = relu(x @ w_in^T + b_in); x0(fp32) = same. Slot-major W.
__global__ __launch_bounds__(512) void in_gemm(const float* __restrict__ x,
                                               const float* __restrict__ w_in,
                                               const float* __restrict__ b_in,
                                               unsigned short* __restrict__ h,
                                               float* __restrict__ x0) {
    __shared__ float4 WI4[32 * HIDC];   // [slot][row], 32KB
    __shared__ float  xs[8][INC];
    int tid = threadIdx.x;
    const float4* wf4 = reinterpret_cast<const float4*>(w_in);
    for (int m = 0; m < 4; ++m) {
        int idx = tid + m * 512;               // idx = s*64 + j
        int s = idx >> 6, j = idx & 63;
        WI4[idx] = wf4[j * 32 + s];
    }
    __syncthreads();
    int w = tid >> 6, lane = tid & 63;
    float bj = b_in[lane];
    for (int n0 = blockIdx.x * 8; n0 < NN; n0 += gridDim.x * 8) {
        int n = n0 + w;
        if (n < NN) {
            xs[w][lane]      = x[(size_t)n * INC + lane];
            xs[w][lane + 64] = x[(size_t)n * INC + 64 + lane];
            WAVE_LDS_FENCE();
            float acc = bj;
            #pragma unroll
            for (int s = 0; s < 32; ++s) {
                float4 wv = WI4[(s << 6) + lane];
                float4 xv = *reinterpret_cast<const float4*>(&xs[w][s << 2]);
                acc = fmaf(wv.x, xv.x, acc);
                acc = fmaf(wv.y, xv.y, acc);
                acc = fmaf(wv.z, xv.z, acc);
                acc = fmaf(wv.w, xv.w, acc);
            }
            float v = fmaxf(acc, 0.0f);
            h[((size_t)n << 6) + lane]  = f2bf(v);
            x0[((size_t)n << 6) + lane] = v;
        }
    }
}

// ---------------------------------------------------------------------------
// Gather core (bf16 rows, batch-4 for load overlap).
__device__ __forceinline__ float4 gather_node(const unsigned short* __restrict__ h_in,
                                              const int2* __restrict__ adj,
                                              int e0, int e1, int g, int c) {
    float4 acc = make_float4(0.f, 0.f, 0.f, 0.f);
    int e = e0 + g;
    for (; e + 16 <= e1; e += 16) {
        int2 a0 = adj[e];
        int2 a1 = adj[e + 4];
        int2 a2 = adj[e + 8];
        int2 a3 = adj[e + 12];
        ushort4 h0 = *reinterpret_cast<const ushort4*>(h_in + ((a0.x << 6) + (c << 2)));
        ushort4 h1 = *reinterpret_cast<const ushort4*>(h_in + ((a1.x << 6) + (c << 2)));
        ushort4 h2 = *reinterpret_cast<const ushort4*>(h_in + ((a2.x << 6) + (c << 2)));
        ushort4 h3 = *reinterpret_cast<const ushort4*>(h_in + ((a3.x << 6) + (c << 2)));
        float n0 = __int_as_float(a0.y), n1 = __int_as_float(a1.y);
        float n2 = __int_as_float(a2.y), n3 = __int_as_float(a3.y);
        acc.x = fmaf(n0, bf2f(h0.x), acc.x); acc.y = fmaf(n0, bf2f(h0.y), acc.y);
        acc.z = fmaf(n0, bf2f(h0.z), acc.z); acc.w = fmaf(n0, bf2f(h0.w), acc.w);
        acc.x = fmaf(n1, bf2f(h1.x), acc.x); acc.y = fmaf(n1, bf2f(h1.y), acc.y);
        acc.z = fmaf(n1, bf2f(h1.z), acc.z); acc.w = fmaf(n1, bf2f(h1.w), acc.w);
        acc.x = fmaf(n2, bf2f(h2.x), acc.x); acc.y = fmaf(n2, bf2f(h2.y), acc.y);
        acc.z = fmaf(n2, bf2f(h2.z), acc.z); acc.w = fmaf(n2, bf2f(h2.w), acc.w);
        acc.x = fmaf(n3, bf2f(h3.x), acc.x); acc.y = fmaf(n3, bf2f(h3.y), acc.y);
        acc.z = fmaf(n3, bf2f(h3.z), acc.z); acc.w = fmaf(n3, bf2f(h3.w), acc.w);
    }
    for (; e < e1; e += 4) {
        int2 a = adj[e];
        ushort4 hv = *reinterpret_cast<const ushort4*>(h_in + ((a.x << 6) + (c << 2)));
        float nrm = __int_as_float(a.y);
        acc.x = fmaf(nrm, bf2f(hv.x), acc.x);
        acc.y = fmaf(nrm, bf2f(hv.y), acc.y);
        acc.z = fmaf(nrm, bf2f(hv.z), acc.z);
        acc.w = fmaf(nrm, bf2f(hv.w), acc.w);
    }
    acc.x += __shfl_xor(acc.x, 16); acc.y += __shfl_xor(acc.y, 16);
    acc.z += __shfl_xor(acc.z, 16); acc.w += __shfl_xor(acc.w, 16);
    acc.x += __shfl_xor(acc.x, 32); acc.y += __shfl_xor(acc.y, 32);
    acc.z += __shfl_xor(acc.z, 32); acc.w += __shfl_xor(acc.w, 32);
    return acc;
}

// Stage 5: GCNII layer (all 8). Dot reads W from REGISTERS (lane j holds row
// j as 16 float4, loaded once per wave) and broadcasts the mixed aggv via
// v_readlane from lanes 0..15 (compile-time indices; k-ascending order ==
// previous summation order). Dot LDS traffic: ~34 b128/node -> ~2 ops/node.
__global__ __launch_bounds__(256, 4) void layer_mid(
        const unsigned short* __restrict__ h_in, unsigned short* __restrict__ h_out,
        const float* __restrict__ x0,
        const int* __restrict__ offsets, const int2* __restrict__ adj,
        const float* __restrict__ W, float beta) {
    __shared__ float4 WI4[16 * HIDC];   // 16KB, staging only
    __shared__ float  vecs[4][HIDC];
    int tid = threadIdx.x;
    const float4* W4 = reinterpret_cast<const float4*>(W);
    for (int m = 0; m < 4; ++m) {
        int idx = tid + m * 256;
        int s = idx >> 6, j = idx & 63;
        WI4[idx] = W4[j * 16 + s];
    }
    __syncthreads();
    int w = tid >> 6, lane = tid & 63;
    float4 wr[16];                       // my W row (64 VGPRs), once per wave
    #pragma unroll
    for (int s = 0; s < 16; ++s) wr[s] = WI4[(s << 6) + lane];
    int g = lane >> 4, c = lane & 15;
    float omb = 1.0f - beta;

    for (int n0 = blockIdx.x * 4; n0 < NN; n0 += gridDim.x * 4) {
        int n = n0 + w;
        if (n < NN) {                    // uniform per wave
            int e0 = offsets[n], e1 = offsets[n + 1];
            float4 acc = gather_node(h_in, adj, e0, e1, g, c);
            // mixed agg in ALL lanes (lanes 0..15 are the readlane sources)
            const float4 x0v = *reinterpret_cast<const float4*>(x0 + ((n << 6) + (c << 2)));
            float4 aggv;
            aggv.x = fmaf(0.9f, acc.x, 0.1f * x0v.x);
            aggv.y = fmaf(0.9f, acc.y, 0.1f * x0v.y);
            aggv.z = fmaf(0.9f, acc.z, 0.1f * x0v.z);
            aggv.w = fmaf(0.9f, acc.w, 0.1f * x0v.w);
            if (g == 0) *reinterpret_cast<float4*>(&vecs[w][c << 2]) = aggv;
            WAVE_LDS_FENCE();
            float vagg = vecs[w][lane];
            float dot = 0.0f;
            #pragma unroll
            for (int k = 0; k < 64; ++k) {
                int sl = k >> 2;
                float av = ((k & 3) == 0) ? rl(aggv.x, sl)
                         : ((k & 3) == 1) ? rl(aggv.y, sl)
                         : ((k & 3) == 2) ? rl(aggv.z, sl)
                                          : rl(aggv.w, sl);
                float wk = ((k & 3) == 0) ? wr[sl].x
                         : ((k & 3) == 1) ? wr[sl].y
                         : ((k & 3) == 2) ? wr[sl].z
                                          : wr[sl].w;
                dot = fmaf(av, wk, dot);
            }
            float hn = fmaxf(fmaf(beta, dot, omb * vagg), 0.0f);
            h_out[(n << 6) + lane] = f2bf(hn);
        }
    }
}

// Stage 6: out = h @ w_out^T + b_out.
__global__ __launch_bounds__(256, 8) void out_gemm(const unsigned short* __restrict__ h,
                                                   const float* __restrict__ w_out,
                                                   const float* __restrict__ b_out,
                                                   float* __restrict__ out) {
    __shared__ float4 WI4[16 * HIDC];
    __shared__ float  vecs[4][HIDC];
    int tid = threadIdx.x;
    const float4* W4 = reinterpret_cast<const float4*>(w_out);
    for (int m = 0; m < 4; ++m) {
        int idx = tid + m * 256;
        int s = idx >> 6, j = idx & 63;
        WI4[idx] = W4[j * 16 + s];
    }
    __syncthreads();
    int w = tid >> 6, lane = tid & 63;
    float bj = b_out[lane];
    for (int n0 = blockIdx.x * 4; n0 < NN; n0 += gridDim.x * 4) {
        int n = n0 + w;
        if (n < NN) {
            vecs[w][lane] = bf2f(h[(n << 6) + lane]);
            WAVE_LDS_FENCE();
            float acc = bj;
            #pragma unroll
            for (int s = 0; s < 16; ++s) {
                float4 wv = WI4[(s << 6) + lane];
                float4 vv = *reinterpret_cast<const float4*>(&vecs[w][s << 2]);
                acc = fmaf(wv.x, vv.x, acc);
                acc = fmaf(wv.y, vv.y, acc);
                acc = fmaf(wv.z, vv.z, acc);
                acc = fmaf(wv.w, vv.w, acc);
            }
            out[(n << 6) + lane] = acc;
        }
    }
}

extern "C" void kernel_launch(void* const* d_in, const int* in_sizes, int n_in,
                              void* d_out, int out_size, void* d_ws, size_t ws_size,
                              hipStream_t stream) {
    const float* x      = (const float*)d_in[0];
    const void*  ei     = d_in[1];
    const float* w_in   = (const float*)d_in[2];
    const float* b_in   = (const float*)d_in[3];
    const float* conv_w = (const float*)d_in[4];
    const float* w_out  = (const float*)d_in[5];
    const float* b_out  = (const float*)d_in[6];
    float* out = (float*)d_out;

    char* ws = (char*)d_ws;
    size_t off = 0;
    auto alloc = [&](size_t bytes) -> void* {
        void* p = ws + off;
        off += (bytes + 255) & ~(size_t)255;
        return p;
    };
    int*   flag    = (int*)alloc(4);
    float* dinv    = (float*)alloc((size_t)NN * 4);
    int*   offsets = (int*)alloc((size_t)(NN + 1) * 4);
    int*   bcnt    = (int*)alloc((size_t)NB * 4);
    int*   bstart  = (int*)alloc((size_t)(NB + 1) * 4);
    int*   bcur    = (int*)alloc((size_t)NB * 4);
    int2*  adj     = (int2*)alloc((size_t)TOT * 8);
    unsigned short* hA = (unsigned short*)alloc((size_t)NN * HIDC * 2);
    unsigned short* hB = (unsigned short*)alloc((size_t)NN * HIDC * 2);
    float* x0      = (float*)alloc((size_t)NN * HIDC * 4);
    // barr (3.4 MB packed) aliases hA (6.4 MB): consumed by bucket_place
    // before in_gemm writes hA.
    unsigned int* barr = (unsigned int*)hA;

    hipMemsetAsync(flag, 0, 4, stream);
    hipMemsetAsync(bcnt, 0, (size_t)NB * 4, stream);
    detect_kernel<<<1, 256, 0, stream>>>((const long long*)ei, flag);
    histA<<<ABLK, 256, 0, stream>>>(ei, flag, bcnt);
    scan_buckets<<<1, 256, 0, stream>>>(bcnt, bstart, bcur);
    bucket_scatter<<<ABLK, 256, 0, stream>>>(ei, flag, bcur, barr);
    bucket_offsets<<<NB, 256, 0, stream>>>(barr, bstart, offsets, dinv);
    bucket_place<<<NB, 256, 0, stream>>>(barr, bstart, offsets, dinv, adj);
    in_gemm<<<1024, 512, 0, stream>>>(x, w_in, b_in, hA, x0);

    unsigned short* cur = hA;
    unsigned short* nxt = hB;
    for (int l = 0; l < LLAYERS; ++l) {
        float beta = logf(0.5f / (float)(l + 1) + 1.0f);
        const float* Wl = conv_w + (size_t)l * HIDC * HIDC;
        layer_mid<<<2048, 256, 0, stream>>>(cur, nxt, x0, offsets, adj, Wl, beta);
        unsigned short* t = cur; cur = nxt; nxt = t;
    }
    out_gemm<<<1024, 256, 0, stream>>>(cur, w_out, b_out, out);
}

// Round 20
// 379.800 us; speedup vs baseline: 1.4381x; 1.4381x over previous
//
#include <hip/hip_runtime.h>
#include <math.h>

#define NN 50000
#define EE 800000
#define INC 128
#define HIDC 64
#define OUTC 64
#define LLAYERS 8
#define TOT (EE + NN)
#define NB 196            // col buckets of 256 cols (196*256 = 50176 >= NN)
#define ABLK 256          // phase-A blocks: 1/CU; runs ~17 entries (~68B, ~2 lines)
#define CHUNKA ((TOT + ABLK - 1) / ABLK)

// Wave-internal LDS fence (vecs[w]/xs[w] wave-private; no block barrier).
#define WAVE_LDS_FENCE() asm volatile("s_waitcnt lgkmcnt(0)" ::: "memory")

// bf16 <-> f32 (RTN-even pack; values are finite)
__device__ __forceinline__ float bf2f(unsigned short u) {
    return __uint_as_float(((unsigned int)u) << 16);
}
__device__ __forceinline__ unsigned short f2bf(float f) {
    unsigned int u = __float_as_uint(f);
    u += 0x7FFFu + ((u >> 16) & 1u);
    return (unsigned short)(u >> 16);
}

// ---------------------------------------------------------------------------
// Stage 0: int64-vs-int32 detect, sampled (256 int64 views; misdetect needs
// 128 consecutive zero odd-words in int32 data: P ~ 0).
__global__ void detect_kernel(const long long* __restrict__ p, int* __restrict__ flag) {
    long long v = p[threadIdx.x];
    if (v < 0 || v >= NN) atomicOr(flag, 1);   // flag=1 -> int32 layout
}

__device__ __forceinline__ int load_row(const void* ei, int is64, int e) {
    return is64 ? (int)((const long long*)ei)[e] : ((const int*)ei)[e];
}
__device__ __forceinline__ int load_col(const void* ei, int is64, int e) {
    return is64 ? (int)((const long long*)ei)[EE + e] : ((const int*)ei)[EE + e];
}

// ---------------------------------------------------------------------------
// CSR build, phase A0: per-bucket edge counts.
__global__ __launch_bounds__(256) void histA(const void* __restrict__ ei,
                                             const int* __restrict__ flag,
                                             int* __restrict__ bcnt) {
    __shared__ int h[NB];
    int tid = threadIdx.x;
    for (int i = tid; i < NB; i += 256) h[i] = 0;
    __syncthreads();
    int is64 = (*flag == 0);
    int lo = blockIdx.x * CHUNKA, hi = lo + CHUNKA; if (hi > TOT) hi = TOT;
    for (int e = lo + tid; e < hi; e += 256) {
        int c = (e < EE) ? load_col(ei, is64, e) : (e - EE);
        atomicAdd(&h[c >> 8], 1);
    }
    __syncthreads();
    for (int i = tid; i < NB; i += 256) if (h[i]) atomicAdd(&bcnt[i], h[i]);
}

// phase A1: exclusive scan of bucket counts -> bstart[NB+1], bcur init.
__global__ __launch_bounds__(256) void scan_buckets(const int* __restrict__ bcnt,
                                                    int* __restrict__ bstart,
                                                    int* __restrict__ bcur) {
    __shared__ int s[256];
    int t = threadIdx.x;
    int v = (t < NB) ? bcnt[t] : 0;
    s[t] = v;
    __syncthreads();
    for (int off = 1; off < 256; off <<= 1) {
        int a = (t >= off) ? s[t - off] : 0;
        __syncthreads();
        s[t] += a;
        __syncthreads();
    }
    if (t < NB) { int st = s[t] - v; bstart[t] = st; bcur[t] = st; }
    if (t == NB - 1) bstart[NB] = s[t];
}

// phase A2: scatter PACKED (src<<8 | col&255) into bucket-major barr.
__global__ __launch_bounds__(256) void bucket_scatter(const void* __restrict__ ei,
                                                      const int* __restrict__ flag,
                                                      int* __restrict__ bcur,
                                                      unsigned int* __restrict__ barr) {
    __shared__ int h[NB];
    __shared__ int base[NB];
    int tid = threadIdx.x;
    for (int i = tid; i < NB; i += 256) h[i] = 0;
    __syncthreads();
    int is64 = (*flag == 0);
    int lo = blockIdx.x * CHUNKA, hi = lo + CHUNKA; if (hi > TOT) hi = TOT;
    for (int e = lo + tid; e < hi; e += 256) {
        int c = (e < EE) ? load_col(ei, is64, e) : (e - EE);
        atomicAdd(&h[c >> 8], 1);
    }
    __syncthreads();
    for (int i = tid; i < NB; i += 256) {
        int cnt = h[i];
        base[i] = cnt ? atomicAdd(&bcur[i], cnt) : 0;
        h[i] = 0;                                   // reuse as local cursor
    }
    __syncthreads();
    for (int e = lo + tid; e < hi; e += 256) {
        int r, c;
        if (e < EE) { r = load_row(ei, is64, e); c = load_col(ei, is64, e); }
        else        { r = e - EE; c = r; }
        int b = c >> 8;
        int p = base[b] + atomicAdd(&h[b], 1);
        barr[p] = ((unsigned int)r << 8) | (unsigned int)(c & 255);
    }
}

// phase B0: per-bucket count + in-block scan -> GLOBAL CSR offsets + dinv.
__global__ __launch_bounds__(256) void bucket_offsets(const unsigned int* __restrict__ barr,
                                                      const int* __restrict__ bstart,
                                                      int* __restrict__ offsets,
                                                      float* __restrict__ dinv) {
    __shared__ int cnt[256];
    __shared__ int pre[256];
    int b = blockIdx.x, t = threadIdx.x;
    cnt[t] = 0;
    __syncthreads();
    int lo = bstart[b], hi = bstart[b + 1];
    for (int i = lo + t; i < hi; i += 256) atomicAdd(&cnt[barr[i] & 255u], 1);
    __syncthreads();
    int v = cnt[t];
    pre[t] = v;
    __syncthreads();
    for (int off = 1; off < 256; off <<= 1) {
        int a = (t >= off) ? pre[t - off] : 0;
        __syncthreads();
        pre[t] += a;
        __syncthreads();
    }
    int c = (b << 8) + t;
    if (c <= NN) offsets[c] = bstart[b] + pre[t] - v;   // exclusive prefix
    if (c < NN)  dinv[c] = 1.0f / sqrtf((float)v);      // deg >= 1 (self-loop)
}

// phase B1: place into adj via LDS cursors (init from offsets).
__global__ __launch_bounds__(256) void bucket_place(const unsigned int* __restrict__ barr,
                                                    const int* __restrict__ bstart,
                                                    const int* __restrict__ offsets,
                                                    const float* __restrict__ dinv,
                                                    int2* __restrict__ adj) {
    __shared__ int cur[256];
    int b = blockIdx.x, t = threadIdx.x;
    int c0 = b << 8;
    int c = c0 + t;
    cur[t] = (c < NN) ? offsets[c] : 0;
    __syncthreads();
    int lo = bstart[b], hi = bstart[b + 1];
    for (int i = lo + t; i < hi; i += 256) {
        unsigned int v = barr[i];
        int r = (int)(v >> 8);
        int ci = (int)(v & 255u);
        int pos = atomicAdd(&cur[ci], 1);
        adj[pos] = make_int2(r, __float_as_int(dinv[r] * dinv[c0 + ci]));
    }
}

// ---------------------------------------------------------------------------
// Stage 4: h(bf16) = relu(x @ w_in^T + b_in); x0(fp32) = same. Slot-major W.
__global__ __launch_bounds__(512) void in_gemm(const float* __restrict__ x,
                                               const float* __restrict__ w_in,
                                               const float* __restrict__ b_in,
                                               unsigned short* __restrict__ h,
                                               float* __restrict__ x0) {
    __shared__ float4 WI4[32 * HIDC];   // [slot][row], 32KB
    __shared__ float  xs[8][INC];
    int tid = threadIdx.x;
    const float4* wf4 = reinterpret_cast<const float4*>(w_in);
    for (int m = 0; m < 4; ++m) {
        int idx = tid + m * 512;               // idx = s*64 + j
        int s = idx >> 6, j = idx & 63;
        WI4[idx] = wf4[j * 32 + s];
    }
    __syncthreads();
    int w = tid >> 6, lane = tid & 63;
    float bj = b_in[lane];
    for (int n0 = blockIdx.x * 8; n0 < NN; n0 += gridDim.x * 8) {
        int n = n0 + w;
        if (n < NN) {
            xs[w][lane]      = x[(size_t)n * INC + lane];
            xs[w][lane + 64] = x[(size_t)n * INC + 64 + lane];
            WAVE_LDS_FENCE();
            float acc = bj;
            #pragma unroll
            for (int s = 0; s < 32; ++s) {
                float4 wv = WI4[(s << 6) + lane];
                float4 xv = *reinterpret_cast<const float4*>(&xs[w][s << 2]);
                acc = fmaf(wv.x, xv.x, acc);
                acc = fmaf(wv.y, xv.y, acc);
                acc = fmaf(wv.z, xv.z, acc);
                acc = fmaf(wv.w, xv.w, acc);
            }
            float v = fmaxf(acc, 0.0f);
            h[((size_t)n << 6) + lane]  = f2bf(v);
            x0[((size_t)n << 6) + lane] = v;
        }
    }
}

// ---------------------------------------------------------------------------
// Gather core (bf16 rows, batch-4 for load overlap).
__device__ __forceinline__ float4 gather_node(const unsigned short* __restrict__ h_in,
                                              const int2* __restrict__ adj,
                                              int e0, int e1, int g, int c) {
    float4 acc = make_float4(0.f, 0.f, 0.f, 0.f);
    int e = e0 + g;
    for (; e + 16 <= e1; e += 16) {
        int2 a0 = adj[e];
        int2 a1 = adj[e + 4];
        int2 a2 = adj[e + 8];
        int2 a3 = adj[e + 12];
        ushort4 h0 = *reinterpret_cast<const ushort4*>(h_in + ((a0.x << 6) + (c << 2)));
        ushort4 h1 = *reinterpret_cast<const ushort4*>(h_in + ((a1.x << 6) + (c << 2)));
        ushort4 h2 = *reinterpret_cast<const ushort4*>(h_in + ((a2.x << 6) + (c << 2)));
        ushort4 h3 = *reinterpret_cast<const ushort4*>(h_in + ((a3.x << 6) + (c << 2)));
        float n0 = __int_as_float(a0.y), n1 = __int_as_float(a1.y);
        float n2 = __int_as_float(a2.y), n3 = __int_as_float(a3.y);
        acc.x = fmaf(n0, bf2f(h0.x), acc.x); acc.y = fmaf(n0, bf2f(h0.y), acc.y);
        acc.z = fmaf(n0, bf2f(h0.z), acc.z); acc.w = fmaf(n0, bf2f(h0.w), acc.w);
        acc.x = fmaf(n1, bf2f(h1.x), acc.x); acc.y = fmaf(n1, bf2f(h1.y), acc.y);
        acc.z = fmaf(n1, bf2f(h1.z), acc.z); acc.w = fmaf(n1, bf2f(h1.w), acc.w);
        acc.x = fmaf(n2, bf2f(h2.x), acc.x); acc.y = fmaf(n2, bf2f(h2.y), acc.y);
        acc.z = fmaf(n2, bf2f(h2.z), acc.z); acc.w = fmaf(n2, bf2f(h2.w), acc.w);
        acc.x = fmaf(n3, bf2f(h3.x), acc.x); acc.y = fmaf(n3, bf2f(h3.y), acc.y);
        acc.z = fmaf(n3, bf2f(h3.z), acc.z); acc.w = fmaf(n3, bf2f(h3.w), acc.w);
    }
    for (; e < e1; e += 4) {
        int2 a = adj[e];
        ushort4 hv = *reinterpret_cast<const ushort4*>(h_in + ((a.x << 6) + (c << 2)));
        float nrm = __int_as_float(a.y);
        acc.x = fmaf(nrm, bf2f(hv.x), acc.x);
        acc.y = fmaf(nrm, bf2f(hv.y), acc.y);
        acc.z = fmaf(nrm, bf2f(hv.z), acc.z);
        acc.w = fmaf(nrm, bf2f(hv.w), acc.w);
    }
    acc.x += __shfl_xor(acc.x, 16); acc.y += __shfl_xor(acc.y, 16);
    acc.z += __shfl_xor(acc.z, 16); acc.w += __shfl_xor(acc.w, 16);
    acc.x += __shfl_xor(acc.x, 32); acc.y += __shfl_xor(acc.y, 32);
    acc.z += __shfl_xor(acc.z, 32); acc.w += __shfl_xor(acc.w, 32);
    return acc;
}

// Stage 5: GCNII layer (all 8). R16's proven slot-major-W LDS b128 dot
// (readlane-broadcast dot regressed twice: R11, R17).
__global__ __launch_bounds__(256, 8) void layer_mid(
        const unsigned short* __restrict__ h_in, unsigned short* __restrict__ h_out,
        const float* __restrict__ x0,
        const int* __restrict__ offsets, const int2* __restrict__ adj,
        const float* __restrict__ W, float beta) {
    __shared__ float4 WI4[16 * HIDC];   // 16KB
    __shared__ float  vecs[4][HIDC];
    int tid = threadIdx.x;
    const float4* W4 = reinterpret_cast<const float4*>(W);
    for (int m = 0; m < 4; ++m) {
        int idx = tid + m * 256;
        int s = idx >> 6, j = idx & 63;
        WI4[idx] = W4[j * 16 + s];
    }
    __syncthreads();
    int w = tid >> 6, lane = tid & 63;
    int g = lane >> 4, c = lane & 15;
    float omb = 1.0f - beta;

    for (int n0 = blockIdx.x * 4; n0 < NN; n0 += gridDim.x * 4) {
        int n = n0 + w;
        if (n < NN) {
            int e0 = offsets[n], e1 = offsets[n + 1];
            float4 acc = gather_node(h_in, adj, e0, e1, g, c);
            if (g == 0) {
                const float4 x0v = *reinterpret_cast<const float4*>(x0 + ((n << 6) + (c << 2)));
                float4 aggv;
                aggv.x = fmaf(0.9f, acc.x, 0.1f * x0v.x);
                aggv.y = fmaf(0.9f, acc.y, 0.1f * x0v.y);
                aggv.z = fmaf(0.9f, acc.z, 0.1f * x0v.z);
                aggv.w = fmaf(0.9f, acc.w, 0.1f * x0v.w);
                *reinterpret_cast<float4*>(&vecs[w][c << 2]) = aggv;
            }
            WAVE_LDS_FENCE();
            float vagg = vecs[w][lane];
            float dot = 0.0f;
            #pragma unroll
            for (int s = 0; s < 16; ++s) {
                float4 wv = WI4[(s << 6) + lane];
                float4 vv = *reinterpret_cast<const float4*>(&vecs[w][s << 2]);
                dot = fmaf(wv.x, vv.x, dot);
                dot = fmaf(wv.y, vv.y, dot);
                dot = fmaf(wv.z, vv.z, dot);
                dot = fmaf(wv.w, vv.w, dot);
            }
            float hn = fmaxf(fmaf(beta, dot, omb * vagg), 0.0f);
            h_out[(n << 6) + lane] = f2bf(hn);
        }
    }
}

// Stage 6: out = h @ w_out^T + b_out.
__global__ __launch_bounds__(256, 8) void out_gemm(const unsigned short* __restrict__ h,
                                                   const float* __restrict__ w_out,
                                                   const float* __restrict__ b_out,
                                                   float* __restrict__ out) {
    __shared__ float4 WI4[16 * HIDC];
    __shared__ float  vecs[4][HIDC];
    int tid = threadIdx.x;
    const float4* W4 = reinterpret_cast<const float4*>(w_out);
    for (int m = 0; m < 4; ++m) {
        int idx = tid + m * 256;
        int s = idx >> 6, j = idx & 63;
        WI4[idx] = W4[j * 16 + s];
    }
    __syncthreads();
    int w = tid >> 6, lane = tid & 63;
    float bj = b_out[lane];
    for (int n0 = blockIdx.x * 4; n0 < NN; n0 += gridDim.x * 4) {
        int n = n0 + w;
        if (n < NN) {
            vecs[w][lane] = bf2f(h[(n << 6) + lane]);
            WAVE_LDS_FENCE();
            float acc = bj;
            #pragma unroll
            for (int s = 0; s < 16; ++s) {
                float4 wv = WI4[(s << 6) + lane];
                float4 vv = *reinterpret_cast<const float4*>(&vecs[w][s << 2]);
                acc = fmaf(wv.x, vv.x, acc);
                acc = fmaf(wv.y, vv.y, acc);
                acc = fmaf(wv.z, vv.z, acc);
                acc = fmaf(wv.w, vv.w, acc);
            }
            out[(n << 6) + lane] = acc;
        }
    }
}

extern "C" void kernel_launch(void* const* d_in, const int* in_sizes, int n_in,
                              void* d_out, int out_size, void* d_ws, size_t ws_size,
                              hipStream_t stream) {
    const float* x      = (const float*)d_in[0];
    const void*  ei     = d_in[1];
    const float* w_in   = (const float*)d_in[2];
    const float* b_in   = (const float*)d_in[3];
    const float* conv_w = (const float*)d_in[4];
    const float* w_out  = (const float*)d_in[5];
    const float* b_out  = (const float*)d_in[6];
    float* out = (float*)d_out;

    char* ws = (char*)d_ws;
    size_t off = 0;
    auto alloc = [&](size_t bytes) -> void* {
        void* p = ws + off;
        off += (bytes + 255) & ~(size_t)255;
        return p;
    };
    int*   flag    = (int*)alloc(4);
    float* dinv    = (float*)alloc((size_t)NN * 4);
    int*   offsets = (int*)alloc((size_t)(NN + 1) * 4);
    int*   bcnt    = (int*)alloc((size_t)NB * 4);
    int*   bstart  = (int*)alloc((size_t)(NB + 1) * 4);
    int*   bcur    = (int*)alloc((size_t)NB * 4);
    int2*  adj     = (int2*)alloc((size_t)TOT * 8);
    unsigned short* hA = (unsigned short*)alloc((size_t)NN * HIDC * 2);
    unsigned short* hB = (unsigned short*)alloc((size_t)NN * HIDC * 2);
    float* x0      = (float*)alloc((size_t)NN * HIDC * 4);
    // barr (3.4 MB packed) aliases hA (6.4 MB): consumed by bucket_place
    // before in_gemm writes hA.
    unsigned int* barr = (unsigned int*)hA;

    hipMemsetAsync(flag, 0, 4, stream);
    hipMemsetAsync(bcnt, 0, (size_t)NB * 4, stream);
    detect_kernel<<<1, 256, 0, stream>>>((const long long*)ei, flag);
    histA<<<ABLK, 256, 0, stream>>>(ei, flag, bcnt);
    scan_buckets<<<1, 256, 0, stream>>>(bcnt, bstart, bcur);
    bucket_scatter<<<ABLK, 256, 0, stream>>>(ei, flag, bcur, barr);
    bucket_offsets<<<NB, 256, 0, stream>>>(barr, bstart, offsets, dinv);
    bucket_place<<<NB, 256, 0, stream>>>(barr, bstart, offsets, dinv, adj);
    in_gemm<<<1024, 512, 0, stream>>>(x, w_in, b_in, hA, x0);

    unsigned short* cur = hA;
    unsigned short* nxt = hB;
    for (int l = 0; l < LLAYERS; ++l) {
        float beta = logf(0.5f / (float)(l + 1) + 1.0f);
        const float* Wl = conv_w + (size_t)l * HIDC * HIDC;
        layer_mid<<<2048, 256, 0, stream>>>(cur, nxt, x0, offsets, adj, Wl, beta);
        unsigned short* t = cur; cur = nxt; nxt = t;
    }
    out_gemm<<<1024, 256, 0, stream>>>(cur, w_out, b_out, out);
}

// Round 23
// 313.159 us; speedup vs baseline: 1.7441x; 1.2128x over previous
//
#include <hip/hip_runtime.h>
#include <math.h>

#define NN 50000
#define EE 800000
#define INC 128
#define HIDC 64
#define OUTC 64
#define LLAYERS 8
#define TOT (EE + NN)
#define NB 196            // col buckets of 256 cols (196*256 = 50176 >= NN)
#define ABLK 256          // phase-A blocks: 1/CU
#define CHUNKA ((TOT + ABLK - 1) / ABLK)

#define WAVE_LDS_FENCE() asm volatile("s_waitcnt lgkmcnt(0)" ::: "memory")

typedef __attribute__((ext_vector_type(8))) short bf16x8;
typedef __attribute__((ext_vector_type(4))) float f32x4;

// bf16 <-> f32 (RTN-even pack; values are finite)
__device__ __forceinline__ float bf2f(unsigned short u) {
    return __uint_as_float(((unsigned int)u) << 16);
}
__device__ __forceinline__ unsigned short f2bf(float f) {
    unsigned int u = __float_as_uint(f);
    u += 0x7FFFu + ((u >> 16) & 1u);
    return (unsigned short)(u >> 16);
}

// ---------------------------------------------------------------------------
// Stage 0: int64-vs-int32 detect, sampled.
__global__ void detect_kernel(const long long* __restrict__ p, int* __restrict__ flag) {
    long long v = p[threadIdx.x];
    if (v < 0 || v >= NN) atomicOr(flag, 1);   // flag=1 -> int32 layout
}

__device__ __forceinline__ int load_row(const void* ei, int is64, int e) {
    return is64 ? (int)((const long long*)ei)[e] : ((const int*)ei)[e];
}
__device__ __forceinline__ int load_col(const void* ei, int is64, int e) {
    return is64 ? (int)((const long long*)ei)[EE + e] : ((const int*)ei)[EE + e];
}

// ---------------------------------------------------------------------------
// CSR build, phase A0: per-bucket edge counts.
__global__ __launch_bounds__(256) void histA(const void* __restrict__ ei,
                                             const int* __restrict__ flag,
                                             int* __restrict__ bcnt) {
    __shared__ int h[NB];
    int tid = threadIdx.x;
    for (int i = tid; i < NB; i += 256) h[i] = 0;
    __syncthreads();
    int is64 = (*flag == 0);
    int lo = blockIdx.x * CHUNKA, hi = lo + CHUNKA; if (hi > TOT) hi = TOT;
    for (int e = lo + tid; e < hi; e += 256) {
        int c = (e < EE) ? load_col(ei, is64, e) : (e - EE);
        atomicAdd(&h[c >> 8], 1);
    }
    __syncthreads();
    for (int i = tid; i < NB; i += 256) if (h[i]) atomicAdd(&bcnt[i], h[i]);
}

// phase A1: exclusive scan of bucket counts -> bstart[NB+1], bcur init.
__global__ __launch_bounds__(256) void scan_buckets(const int* __restrict__ bcnt,
                                                    int* __restrict__ bstart,
                                                    int* __restrict__ bcur) {
    __shared__ int s[256];
    int t = threadIdx.x;
    int v = (t < NB) ? bcnt[t] : 0;
    s[t] = v;
    __syncthreads();
    for (int off = 1; off < 256; off <<= 1) {
        int a = (t >= off) ? s[t - off] : 0;
        __syncthreads();
        s[t] += a;
        __syncthreads();
    }
    if (t < NB) { int st = s[t] - v; bstart[t] = st; bcur[t] = st; }
    if (t == NB - 1) bstart[NB] = s[t];
}

// phase A2: scatter PACKED (src<<8 | col&255) into bucket-major barr.
__global__ __launch_bounds__(256) void bucket_scatter(const void* __restrict__ ei,
                                                      const int* __restrict__ flag,
                                                      int* __restrict__ bcur,
                                                      unsigned int* __restrict__ barr) {
    __shared__ int h[NB];
    __shared__ int base[NB];
    int tid = threadIdx.x;
    for (int i = tid; i < NB; i += 256) h[i] = 0;
    __syncthreads();
    int is64 = (*flag == 0);
    int lo = blockIdx.x * CHUNKA, hi = lo + CHUNKA; if (hi > TOT) hi = TOT;
    for (int e = lo + tid; e < hi; e += 256) {
        int c = (e < EE) ? load_col(ei, is64, e) : (e - EE);
        atomicAdd(&h[c >> 8], 1);
    }
    __syncthreads();
    for (int i = tid; i < NB; i += 256) {
        int cnt = h[i];
        base[i] = cnt ? atomicAdd(&bcur[i], cnt) : 0;
        h[i] = 0;                                   // reuse as local cursor
    }
    __syncthreads();
    for (int e = lo + tid; e < hi; e += 256) {
        int r, c;
        if (e < EE) { r = load_row(ei, is64, e); c = load_col(ei, is64, e); }
        else        { r = e - EE; c = r; }
        int b = c >> 8;
        int p = base[b] + atomicAdd(&h[b], 1);
        barr[p] = ((unsigned int)r << 8) | (unsigned int)(c & 255);
    }
}

// phase B0: per-bucket count + in-block scan -> GLOBAL CSR offsets + dinv.
__global__ __launch_bounds__(256) void bucket_offsets(const unsigned int* __restrict__ barr,
                                                      const int* __restrict__ bstart,
                                                      int* __restrict__ offsets,
                                                      float* __restrict__ dinv) {
    __shared__ int cnt[256];
    __shared__ int pre[256];
    int b = blockIdx.x, t = threadIdx.x;
    cnt[t] = 0;
    __syncthreads();
    int lo = bstart[b], hi = bstart[b + 1];
    for (int i = lo + t; i < hi; i += 256) atomicAdd(&cnt[barr[i] & 255u], 1);
    __syncthreads();
    int v = cnt[t];
    pre[t] = v;
    __syncthreads();
    for (int off = 1; off < 256; off <<= 1) {
        int a = (t >= off) ? pre[t - off] : 0;
        __syncthreads();
        pre[t] += a;
        __syncthreads();
    }
    int c = (b << 8) + t;
    if (c <= NN) offsets[c] = bstart[b] + pre[t] - v;   // exclusive prefix
    if (c < NN)  dinv[c] = 1.0f / sqrtf((float)v);      // deg >= 1 (self-loop)
}

// phase B1: place into adj via LDS cursors (init from offsets).
__global__ __launch_bounds__(256) void bucket_place(const unsigned int* __restrict__ barr,
                                                    const int* __restrict__ bstart,
                                                    const int* __restrict__ offsets,
                                                    const float* __restrict__ dinv,
                                                    int2* __restrict__ adj) {
    __shared__ int cur[256];
    int b = blockIdx.x, t = threadIdx.x;
    int c0 = b << 8;
    int c = c0 + t;
    cur[t] = (c < NN) ? offsets[c] : 0;
    __syncthreads();
    int lo = bstart[b], hi = bstart[b + 1];
    for (int i = lo + t; i < hi; i += 256) {
        unsigned int v = barr[i];
        int r = (int)(v >> 8);
        int ci = (int)(v & 255u);
        int pos = atomicAdd(&cur[ci], 1);
        adj[pos] = make_int2(r, __float_as_int(dinv[r] * dinv[c0 + ci]));
    }
}

// ---------------------------------------------------------------------------
// Stage 4: h(bf16) = relu(x @ w_in^T + b_in); x0(fp32) = same. Slot-major W.
__global__ __launch_bounds__(512) void in_gemm(const float* __restrict__ x,
                                               const float* __restrict__ w_in,
                                               const float* __restrict__ b_in,
                                               unsigned short* __restrict__ h,
                                               float* __restrict__ x0) {
    __shared__ float4 WI4[32 * HIDC];   // [slot][row], 32KB
    __shared__ float  xs[8][INC];
    int tid = threadIdx.x;
    const float4* wf4 = reinterpret_cast<const float4*>(w_in);
    for (int m = 0; m < 4; ++m) {
        int idx = tid + m * 512;               // idx = s*64 + j
        int s = idx >> 6, j = idx & 63;
        WI4[idx] = wf4[j * 32 + s];
    }
    __syncthreads();
    int w = tid >> 6, lane = tid & 63;
    float bj = b_in[lane];
    for (int n0 = blockIdx.x * 8; n0 < NN; n0 += gridDim.x * 8) {
        int n = n0 + w;
        if (n < NN) {
            xs[w][lane]      = x[(size_t)n * INC + lane];
            xs[w][lane + 64] = x[(size_t)n * INC + 64 + lane];
            WAVE_LDS_FENCE();
            float acc = bj;
            #pragma unroll
            for (int s = 0; s < 32; ++s) {
                float4 wv = WI4[(s << 6) + lane];
                float4 xv = *reinterpret_cast<const float4*>(&xs[w][s << 2]);
                acc = fmaf(wv.x, xv.x, acc);
                acc = fmaf(wv.y, xv.y, acc);
                acc = fmaf(wv.z, xv.z, acc);
                acc = fmaf(wv.w, xv.w, acc);
            }
            float v = fmaxf(acc, 0.0f);
            h[((size_t)n << 6) + lane]  = f2bf(v);
            x0[((size_t)n << 6) + lane] = v;
        }
    }
}

// ---------------------------------------------------------------------------
// Stage 5: GCNII layer via MFMA. Block = 4 waves = 16 nodes (grid 3125 exact).
// out = relu(agg @ Wt), Wt = beta*W^T + (1-beta)*I folded into the B operand.
// Group g of wave w gathers node base+w*4+g fully (lane c = channel quad; no
// cross-lane reduce). agg -> bf16 LDS tile [16][72] (144B=9*16B rows: aligned,
// 2-way-conflict-free A-frag reads). B-fragments built once from global W.
__global__ __launch_bounds__(256) void layer_mfma(
        const unsigned short* __restrict__ h_in, unsigned short* __restrict__ h_out,
        const float* __restrict__ x0,
        const int* __restrict__ offsets, const int2* __restrict__ adj,
        const float* __restrict__ W, float beta) {
    __shared__ unsigned short aggT[16 * 72];
    int tid = threadIdx.x, w = tid >> 6, lane = tid & 63;
    int g = lane >> 4, c = lane & 15;
    float omb = 1.0f - beta;

    // B fragments: lane holds B[k][n] = beta*W[n][k] + (1-beta)*delta(k,n),
    // n = w*16 + (lane&15), k = kt*32 + (lane>>4)*8 + i  (bf16, from global W)
    bf16x8 bfrag[2];
    {
        int n = (w << 4) + c;
        const float* Wrow = W + n * HIDC;
        #pragma unroll
        for (int kt = 0; kt < 2; ++kt) {
            int k0 = kt * 32 + (g << 3);
            float4 va = *reinterpret_cast<const float4*>(Wrow + k0);
            float4 vb = *reinterpret_cast<const float4*>(Wrow + k0 + 4);
            float e[8] = {va.x, va.y, va.z, va.w, vb.x, vb.y, vb.z, vb.w};
            bf16x8 r;
            #pragma unroll
            for (int i = 0; i < 8; ++i) {
                float t = beta * e[i] + ((k0 + i == n) ? omb : 0.0f);
                r[i] = (short)f2bf(t);
            }
            bfrag[kt] = r;
        }
    }

    // Gather: group g handles node base + w*4 + g; lane c owns channels c*4..+3.
    int base = blockIdx.x << 4;
    int n = base + (w << 2) + g;
    int e0 = offsets[n], e1 = offsets[n + 1];
    float4 acc = make_float4(0.f, 0.f, 0.f, 0.f);
    int e = e0;
    for (; e + 4 <= e1; e += 4) {
        int2 a0 = adj[e], a1 = adj[e + 1], a2 = adj[e + 2], a3 = adj[e + 3];
        ushort4 h0 = *reinterpret_cast<const ushort4*>(h_in + ((a0.x << 6) + (c << 2)));
        ushort4 h1 = *reinterpret_cast<const ushort4*>(h_in + ((a1.x << 6) + (c << 2)));
        ushort4 h2 = *reinterpret_cast<const ushort4*>(h_in + ((a2.x << 6) + (c << 2)));
        ushort4 h3 = *reinterpret_cast<const ushort4*>(h_in + ((a3.x << 6) + (c << 2)));
        float n0 = __int_as_float(a0.y), n1 = __int_as_float(a1.y);
        float n2 = __int_as_float(a2.y), n3 = __int_as_float(a3.y);
        acc.x = fmaf(n0, bf2f(h0.x), acc.x); acc.y = fmaf(n0, bf2f(h0.y), acc.y);
        acc.z = fmaf(n0, bf2f(h0.z), acc.z); acc.w = fmaf(n0, bf2f(h0.w), acc.w);
        acc.x = fmaf(n1, bf2f(h1.x), acc.x); acc.y = fmaf(n1, bf2f(h1.y), acc.y);
        acc.z = fmaf(n1, bf2f(h1.z), acc.z); acc.w = fmaf(n1, bf2f(h1.w), acc.w);
        acc.x = fmaf(n2, bf2f(h2.x), acc.x); acc.y = fmaf(n2, bf2f(h2.y), acc.y);
        acc.z = fmaf(n2, bf2f(h2.z), acc.z); acc.w = fmaf(n2, bf2f(h2.w), acc.w);
        acc.x = fmaf(n3, bf2f(h3.x), acc.x); acc.y = fmaf(n3, bf2f(h3.y), acc.y);
        acc.z = fmaf(n3, bf2f(h3.z), acc.z); acc.w = fmaf(n3, bf2f(h3.w), acc.w);
    }
    for (; e < e1; ++e) {
        int2 a = adj[e];
        ushort4 hv = *reinterpret_cast<const ushort4*>(h_in + ((a.x << 6) + (c << 2)));
        float nrm = __int_as_float(a.y);
        acc.x = fmaf(nrm, bf2f(hv.x), acc.x);
        acc.y = fmaf(nrm, bf2f(hv.y), acc.y);
        acc.z = fmaf(nrm, bf2f(hv.z), acc.z);
        acc.w = fmaf(nrm, bf2f(hv.w), acc.w);
    }
    {
        const float4 x0v = *reinterpret_cast<const float4*>(x0 + ((n << 6) + (c << 2)));
        ushort4 pk;
        pk.x = f2bf(fmaf(0.9f, acc.x, 0.1f * x0v.x));
        pk.y = f2bf(fmaf(0.9f, acc.y, 0.1f * x0v.y));
        pk.z = f2bf(fmaf(0.9f, acc.z, 0.1f * x0v.z));
        pk.w = f2bf(fmaf(0.9f, acc.w, 0.1f * x0v.w));
        int row = (w << 2) + g;
        *reinterpret_cast<ushort4*>(&aggT[row * 72 + (c << 2)]) = pk;
    }
    __syncthreads();

    // A fragments: lane holds A[m][k], m = lane&15, k = kt*32 + (lane>>4)*8 + i
    bf16x8 afrag0 = *reinterpret_cast<const bf16x8*>(&aggT[c * 72 + (g << 3)]);
    bf16x8 afrag1 = *reinterpret_cast<const bf16x8*>(&aggT[c * 72 + 32 + (g << 3)]);

    f32x4 d = {0.f, 0.f, 0.f, 0.f};
    d = __builtin_amdgcn_mfma_f32_16x16x32_bf16(afrag0, bfrag[0], d, 0, 0, 0);
    d = __builtin_amdgcn_mfma_f32_16x16x32_bf16(afrag1, bfrag[1], d, 0, 0, 0);

    // D layout (m89-verified): col = lane&15, row = (lane>>4)*4 + reg.
    #pragma unroll
    for (int r = 0; r < 4; ++r) {
        int node = base + (g << 2) + r;
        int ch = (w << 4) + c;
        h_out[(node << 6) + ch] = f2bf(fmaxf(d[r], 0.0f));
    }
}

// Stage 6: out = h @ w_out^T + b_out.
__global__ __launch_bounds__(256, 8) void out_gemm(const unsigned short* __restrict__ h,
                                                   const float* __restrict__ w_out,
                                                   const float* __restrict__ b_out,
                                                   float* __restrict__ out) {
    __shared__ float4 WI4[16 * HIDC];
    __shared__ float  vecs[4][HIDC];
    int tid = threadIdx.x;
    const float4* W4 = reinterpret_cast<const float4*>(w_out);
    for (int m = 0; m < 4; ++m) {
        int idx = tid + m * 256;
        int s = idx >> 6, j = idx & 63;
        WI4[idx] = W4[j * 16 + s];
    }
    __syncthreads();
    int w = tid >> 6, lane = tid & 63;
    float bj = b_out[lane];
    for (int n0 = blockIdx.x * 4; n0 < NN; n0 += gridDim.x * 4) {
        int n = n0 + w;
        if (n < NN) {
            vecs[w][lane] = bf2f(h[(n << 6) + lane]);
            WAVE_LDS_FENCE();
            float acc = bj;
            #pragma unroll
            for (int s = 0; s < 16; ++s) {
                float4 wv = WI4[(s << 6) + lane];
                float4 vv = *reinterpret_cast<const float4*>(&vecs[w][s << 2]);
                acc = fmaf(wv.x, vv.x, acc);
                acc = fmaf(wv.y, vv.y, acc);
                acc = fmaf(wv.z, vv.z, acc);
                acc = fmaf(wv.w, vv.w, acc);
            }
            out[(n << 6) + lane] = acc;
        }
    }
}

extern "C" void kernel_launch(void* const* d_in, const int* in_sizes, int n_in,
                              void* d_out, int out_size, void* d_ws, size_t ws_size,
                              hipStream_t stream) {
    const float* x      = (const float*)d_in[0];
    const void*  ei     = d_in[1];
    const float* w_in   = (const float*)d_in[2];
    const float* b_in   = (const float*)d_in[3];
    const float* conv_w = (const float*)d_in[4];
    const float* w_out  = (const float*)d_in[5];
    const float* b_out  = (const float*)d_in[6];
    float* out = (float*)d_out;

    char* ws = (char*)d_ws;
    size_t off = 0;
    auto alloc = [&](size_t bytes) -> void* {
        void* p = ws + off;
        off += (bytes + 255) & ~(size_t)255;
        return p;
    };
    int*   flag    = (int*)alloc(4);
    float* dinv    = (float*)alloc((size_t)NN * 4);
    int*   offsets = (int*)alloc((size_t)(NN + 1) * 4);
    int*   bcnt    = (int*)alloc((size_t)NB * 4);
    int*   bstart  = (int*)alloc((size_t)(NB + 1) * 4);
    int*   bcur    = (int*)alloc((size_t)NB * 4);
    int2*  adj     = (int2*)alloc((size_t)TOT * 8);
    unsigned short* hA = (unsigned short*)alloc((size_t)NN * HIDC * 2);
    unsigned short* hB = (unsigned short*)alloc((size_t)NN * HIDC * 2);
    float* x0      = (float*)alloc((size_t)NN * HIDC * 4);
    // barr (3.4 MB packed) aliases hA (6.4 MB): consumed by bucket_place
    // before in_gemm writes hA.
    unsigned int* barr = (unsigned int*)hA;

    hipMemsetAsync(flag, 0, 4, stream);
    hipMemsetAsync(bcnt, 0, (size_t)NB * 4, stream);
    detect_kernel<<<1, 256, 0, stream>>>((const long long*)ei, flag);
    histA<<<ABLK, 256, 0, stream>>>(ei, flag, bcnt);
    scan_buckets<<<1, 256, 0, stream>>>(bcnt, bstart, bcur);
    bucket_scatter<<<ABLK, 256, 0, stream>>>(ei, flag, bcur, barr);
    bucket_offsets<<<NB, 256, 0, stream>>>(barr, bstart, offsets, dinv);
    bucket_place<<<NB, 256, 0, stream>>>(barr, bstart, offsets, dinv, adj);
    in_gemm<<<1024, 512, 0, stream>>>(x, w_in, b_in, hA, x0);

    unsigned short* cur = hA;
    unsigned short* nxt = hB;
    for (int l = 0; l < LLAYERS; ++l) {
        float beta = logf(0.5f / (float)(l + 1) + 1.0f);
        const float* Wl = conv_w + (size_t)l * HIDC * HIDC;
        layer_mfma<<<NN / 16, 256, 0, stream>>>(cur, nxt, x0, offsets, adj, Wl, beta);
        unsigned short* t = cur; cur = nxt; nxt = t;
    }
    out_gemm<<<1024, 256, 0, stream>>>(cur, w_out, b_out, out);
}